// Round 1
// 83.474 us; speedup vs baseline: 1.0088x; 1.0088x over previous
//
#include <hip/hip_runtime.h>

// Chamfer distance loss over equal-size clusters (C=128, P=1024, DIM=3).
// Reference excludes the highest cluster id -> clusters 0..126 contribute.
//
// R4 structure: one block per (cluster, direction) = 254 blocks, 1024 threads.
// Change vs R3: Q 8->16 queries/thread (QG 128->64, SEG 8->16). One
// ds_read_b128 broadcast now feeds 16 queries, halving inner-loop LDS-pipe
// time (was ~10us/CU vs ~12us VALU -- nearly co-critical) and doubling the
// VALU work per load batch for latency tolerance. jj-unroll reduced 4->2 to
// keep live float4 staging at 16 VGPRs (total ~110, under the 128 cap from
// the 1024-thread launch bounds; a spill here would be fatal).
// pm grows to 64KB (80KB LDS total) -> still 1 block/CU, matching the grid.

#define PTS 1024
#define ACTIVE_CLUSTERS 127
#define QG   64             // queries per k-slice (= threads per segment)
#define Q    16             // queries per thread
#define SEG  16             // target segments (one wave per segment)
#define TPB  1024           // QG * SEG
#define TSEG (PTS / SEG)    // targets per segment = 64

__global__ __launch_bounds__(TPB) void chamfer_kernel(
    const float* __restrict__ pts_in,
    const float* __restrict__ pts_out,
    float* __restrict__ out)
{
    const int c   = blockIdx.x >> 1;
    const int dir = blockIdx.x & 1;

    const float* __restrict__ query  = dir ? pts_out : pts_in;
    const float* __restrict__ target = dir ? pts_in  : pts_out;

    __shared__ __align__(16) float4 st[PTS];      // 16 KB: (x,y,z,|b|^2)
    __shared__ float pm[SEG * Q * QG];            // 64 KB: partial mins

    const int tid = threadIdx.x;
    const int qi  = tid & (QG - 1);
    const int seg = tid >> 6;                     // == wave id
    const size_t base = (size_t)c * PTS * 3;

    // Stage all 1024 targets: one point per thread.
    {
        const float* tp = target + base + (size_t)tid * 3;
        float x = tp[0], y = tp[1], z = tp[2];
        st[tid] = make_float4(x, y, z, fmaf(x, x, fmaf(y, y, z * z)));
    }

    // Load this thread's Q query points (as -2*coords and |a|^2).
    float qx[Q], qy[Q], qz[Q], qn[Q], mn[Q];
    #pragma unroll
    for (int k = 0; k < Q; ++k) {
        const float* qp = query + base + (size_t)(k * QG + qi) * 3;
        float ax = qp[0], ay = qp[1], az = qp[2];
        qn[k] = fmaf(ax, ax, fmaf(ay, ay, az * az));
        qx[k] = -2.0f * ax;
        qy[k] = -2.0f * ay;
        qz[k] = -2.0f * az;
        mn[k] = 3.4e38f;
    }
    __syncthreads();

    // Sweep this segment's targets, unrolled by 2 for v_min3 fusion.
    // Per b128-broadcast pair: 16 queries x 7 VALU = 112 ops (was 56).
    const int j0 = seg * TSEG;
    #pragma unroll 2
    for (int jj = 0; jj < TSEG; jj += 2) {
        const float4 b0 = st[j0 + jj];
        const float4 b1 = st[j0 + jj + 1];
        #pragma unroll
        for (int k = 0; k < Q; ++k) {
            float s0 = fmaf(qx[k], b0.x, b0.w);
            s0 = fmaf(qy[k], b0.y, s0);
            s0 = fmaf(qz[k], b0.z, s0);
            float s1 = fmaf(qx[k], b1.x, b1.w);
            s1 = fmaf(qy[k], b1.y, s1);
            s1 = fmaf(qz[k], b1.z, s1);
            mn[k] = fminf(fminf(s0, s1), mn[k]);   // -> v_min3_f32
        }
    }

    // Store partial mins with |a|^2 pre-added (min distributes over +const).
    #pragma unroll
    for (int k = 0; k < Q; ++k)
        pm[(seg * Q + k) * QG + qi] = mn[k] + qn[k];
    __syncthreads();

    // Combine: thread tid owns query q = tid -> (k = q>>6, qi2 = q&63).
    const int k2  = tid >> 6;
    const int qi2 = tid & (QG - 1);
    float v = 3.4e38f;
    #pragma unroll
    for (int s = 0; s < SEG; ++s)
        v = fminf(v, pm[(s * Q + k2) * QG + qi2]);

    // Block sum: wave shuffle, cross-wave via LDS, one atomicAdd.
    #pragma unroll
    for (int off = 32; off > 0; off >>= 1)
        v += __shfl_down(v, off, 64);

    __shared__ float wsum[16];
    const int wave = tid >> 6;
    const int lane = tid & 63;
    if (lane == 0) wsum[wave] = v;
    __syncthreads();

    if (wave == 0) {
        float t = (lane < 16) ? wsum[lane] : 0.0f;
        #pragma unroll
        for (int off = 8; off > 0; off >>= 1)
            t += __shfl_down(t, off, 64);
        if (lane == 0) atomicAdd(out, t);
    }
}

extern "C" void kernel_launch(void* const* d_in, const int* in_sizes, int n_in,
                              void* d_out, int out_size, void* d_ws, size_t ws_size,
                              hipStream_t stream) {
    const float* input_points  = (const float*)d_in[0];
    const float* output_points = (const float*)d_in[2];
    float* out = (float*)d_out;

    hipMemsetAsync(out, 0, sizeof(float), stream);

    chamfer_kernel<<<dim3(ACTIVE_CLUSTERS * 2), dim3(TPB), 0, stream>>>(
        input_points, output_points, out);
}